// Round 5
// baseline (462.629 us; speedup 1.0000x reference)
//
#include <hip/hip_runtime.h>
#include <hip/hip_bf16.h>
#include <stdint.h>

// ---------------------------------------------------------------------------
// GCN forward: 3 layers of  out = Ahat * (X @ W) + b, relu between layers.
// Factored normalization: out[d] = dinv[d]*( sum_{s in in(d)} H'[s] + H'[d] ) + b
// where H'[i] = bf16( dinv[i] * (X@W)[i] ).
// GEMM: MFMA bf16 hi/lo split (3 mfma per product -> ~fp32 precision).
// CSR build: XCD-sharded degree+rank atomics (each XCD owns a private count
// plane -> no cross-XCD L2 line ping-pong), merge -> deg/dinv/shard-prefix,
// hierarchical scan, atomic-free scatter.
// Aggregation: wave-per-node CSR gather of bf16 rows, f32 accumulate.
// ---------------------------------------------------------------------------

typedef __attribute__((ext_vector_type(8))) short bf16x8;
typedef __attribute__((ext_vector_type(4))) float f32x4;

__device__ __forceinline__ float bflo(uint32_t u) { return __uint_as_float(u << 16); }
__device__ __forceinline__ float bfhi(uint32_t u) { return __uint_as_float(u & 0xffff0000u); }
__device__ __forceinline__ unsigned short f2bf(float f) {
    uint32_t x = __float_as_uint(f);
    return (unsigned short)((x + 0x7fffu + ((x >> 16) & 1u)) >> 16);
}

__device__ __forceinline__ int xcc_id() {
    int x;
    asm volatile("s_getreg_b32 %0, hwreg(HW_REG_XCC_ID)" : "=s"(x));
    return x & 7;
}

// degree count sharded by physical XCD + per-edge (shard,rank) pack
__global__ __launch_bounds__(256) void k_deg_rank(const int* __restrict__ dst,
                                                  int* __restrict__ scnt,
                                                  int* __restrict__ rank,
                                                  int N, int E) {
    int e = blockIdx.x * 256 + threadIdx.x;
    int xc = xcc_id();
    if (e < E) {
        int r = atomicAdd(&scnt[xc * N + dst[e]], 1);
        rank[e] = (xc << 28) | r;
    }
}

// shard counts -> exclusive shard prefix (in place); deg, dinv out.
__global__ __launch_bounds__(256) void k_merge(int* __restrict__ scnt,
                                               int* __restrict__ deg,
                                               float* __restrict__ dinv, int N) {
    int i = blockIdx.x * 256 + threadIdx.x;
    if (i >= N) return;
    int sum = 0;
#pragma unroll
    for (int s = 0; s < 8; ++s) {
        int c = scnt[s * N + i];
        scnt[s * N + i] = sum;
        sum += c;
    }
    deg[i] = sum;
    dinv[i] = rsqrtf((float)(sum + 1));  // +1 self-loop
}

// ---- hierarchical scan: 1024 elements per block ---------------------------
__global__ __launch_bounds__(256) void k_scan_local(const int* __restrict__ deg,
                                                    int* __restrict__ incl,
                                                    int* __restrict__ bsum, int N) {
    __shared__ int part[256];
    int t = threadIdx.x;
    int idx0 = blockIdx.x * 1024 + t * 4;
    int4 lv = {0, 0, 0, 0};
    if (idx0 + 4 <= N) {
        lv = *(const int4*)&deg[idx0];
    } else {
        int* pv = (int*)&lv;
        for (int i = 0; i < 4; ++i) pv[i] = (idx0 + i < N) ? deg[idx0 + i] : 0;
    }
    int s = lv.x + lv.y + lv.z + lv.w;
    part[t] = s;
    __syncthreads();
    for (int off = 1; off < 256; off <<= 1) {
        int x = (t >= off) ? part[t - off] : 0;
        __syncthreads();
        part[t] += x;
        __syncthreads();
    }
    int run = (t == 0) ? 0 : part[t - 1];
    if (t == 255) bsum[blockIdx.x] = part[255];
    int4 ov;
    ov.x = run + lv.x;
    ov.y = ov.x + lv.y;
    ov.z = ov.y + lv.z;
    ov.w = ov.z + lv.w;
    if (idx0 + 4 <= N) {
        *(int4*)&incl[idx0] = ov;
    } else {
        int* po = (int*)&ov;
        for (int i = 0; i < 4; ++i)
            if (idx0 + i < N) incl[idx0 + i] = po[i];
    }
}

// exclusive scan of up to 256 block sums; also writes row_ptr[N] = total
__global__ __launch_bounds__(256) void k_scan_tops(int* __restrict__ bsum, int nb,
                                                   int* __restrict__ row_ptr, int N) {
    __shared__ int part[256];
    int t = threadIdx.x;
    int v = (t < nb) ? bsum[t] : 0;
    part[t] = v;
    __syncthreads();
    for (int off = 1; off < 256; off <<= 1) {
        int x = (t >= off) ? part[t - off] : 0;
        __syncthreads();
        part[t] += x;
        __syncthreads();
    }
    if (t < nb) bsum[t] = part[t] - v;   // exclusive
    if (t == 255) row_ptr[N] = part[255];
}

__global__ __launch_bounds__(256) void k_scan_final(const int* __restrict__ incl,
                                                    const int* __restrict__ deg,
                                                    const int* __restrict__ bsum,
                                                    int* __restrict__ row_ptr, int N) {
    int i = blockIdx.x * 256 + threadIdx.x;
    if (i < N) row_ptr[i] = incl[i] - deg[i] + bsum[i >> 10];
}

// atomic-free scatter: pos = row_ptr[dst] + shard_prefix + local rank
__global__ __launch_bounds__(256) void k_scatter(const int* __restrict__ src,
                                                 const int* __restrict__ dst,
                                                 const int* __restrict__ rank,
                                                 const int* __restrict__ row_ptr,
                                                 const int* __restrict__ scnt,
                                                 int* __restrict__ col_idx,
                                                 int N, int E) {
    int e = blockIdx.x * 256 + threadIdx.x;
    if (e < E) {
        int d = dst[e];
        int pr = rank[e];
        int s = pr >> 28, lr = pr & 0x0fffffff;
        col_idx[row_ptr[d] + scnt[s * N + d] + lr] = src[e];
    }
}

// W [K][M] f32 -> Wt_hi[c][k], Wt_lo[c][k] bf16 (transposed, hi plane then lo)
__global__ __launch_bounds__(256) void k_prepw(const float* __restrict__ W0,
                                               const float* __restrict__ W1,
                                               const float* __restrict__ W2,
                                               unsigned short* __restrict__ wt0,
                                               unsigned short* __restrict__ wt1,
                                               unsigned short* __restrict__ wt2) {
    int id = blockIdx.x * 256 + threadIdx.x;
    const float* Wsrc;
    unsigned short* dst;
    int t, M, plane;
    if (id < 16384)      { t = id;         Wsrc = W0; dst = wt0; M = 128; plane = 16384; }
    else if (id < 32768) { t = id - 16384; Wsrc = W1; dst = wt1; M = 128; plane = 16384; }
    else if (id < 40960) { t = id - 32768; Wsrc = W2; dst = wt2; M = 64;  plane = 8192;  }
    else return;
    int k = (M == 128) ? (t >> 7) : (t >> 6);
    int c = (M == 128) ? (t & 127) : (t & 63);
    float v = Wsrc[k * M + c];
    unsigned short hi = f2bf(v);
    float lov = v - bflo((uint32_t)hi);
    dst[c * 128 + k]         = hi;
    dst[plane + c * 128 + k] = f2bf(lov);
}

// H[r,:] = bf16( dinv[r] * (A[r,:] @ W) ) via split-bf16 MFMA.
// A f32 [N,128]; Wt = transposed hi/lo bf16 [NCOL][128] x2; H bf16 [N,NCOL].
// Block: 256 thr / 4 waves, tile 128 rows x NCOL cols, K-tiled by 64.
template <int NCOL>
__global__ __launch_bounds__(256) void k_gemm_mfma(
    const float* __restrict__ A, const unsigned short* __restrict__ Wt,
    const float* __restrict__ dinv, unsigned short* __restrict__ H, int N) {
    constexpr int K = 128, KT = 64;
    constexpr int A_PLANE = 128 * KT;     // shorts
    constexpr int W_PLANE = NCOL * KT;
    __shared__ __align__(16) unsigned short sm[2 * A_PLANE + 2 * W_PLANE];  // 64/48 KB
    unsigned short* Ah  = sm;
    unsigned short* Al  = sm + A_PLANE;
    unsigned short* Whp = sm + 2 * A_PLANE;
    unsigned short* Wlp = sm + 2 * A_PLANE + W_PLANE;

    const int tid = threadIdx.x;
    const long r0 = (long)blockIdx.x * 128;
    const int w = tid >> 6, l = tid & 63;
    const int lr = l & 15, lk = l >> 4;
    constexpr int WR = (NCOL == 128) ? 4 : 2;          // 16-row frags per wave
    const int wrow = (NCOL == 128) ? (w >> 1) * 64 : w * 32;
    const int wcol = (NCOL == 128) ? (w & 1) * 64 : 0;

    f32x4 acc[WR][4];
#pragma unroll
    for (int i = 0; i < WR; ++i)
#pragma unroll
        for (int j = 0; j < 4; ++j) acc[i][j] = (f32x4){0.f, 0.f, 0.f, 0.f};

    for (int kt = 0; kt < 2; ++kt) {
        if (kt) __syncthreads();           // previous compute done
        // ---- stage A tile: 128 rows x 64 k, f32 -> hi/lo bf16, swizzled ----
#pragma unroll
        for (int it = 0; it < 4; ++it) {
            int id = it * 256 + tid;
            int r = id >> 3, kc = id & 7;   // 8 chunks of 8 f32 per row
            long gr = r0 + r;
            if (gr >= N) gr = N - 1;
            const float* ap = &A[gr * K + kt * KT + kc * 8];
            float4 v0 = *(const float4*)ap;
            float4 v1 = *(const float4*)(ap + 4);
            float vv[8] = {v0.x, v0.y, v0.z, v0.w, v1.x, v1.y, v1.z, v1.w};
            union { unsigned short u[8]; bf16x8 v; } ph, pl;
#pragma unroll
            for (int j = 0; j < 8; ++j) {
                unsigned short h = f2bf(vv[j]);
                ph.u[j] = h;
                pl.u[j] = f2bf(vv[j] - bflo((uint32_t)h));
            }
            int boff = r * 128 + ((kc * 16) ^ ((r & 7) << 4));
            *(bf16x8*)((char*)Ah + boff) = ph.v;
            *(bf16x8*)((char*)Al + boff) = pl.v;
        }
        // ---- stage W tile: NCOL rows x 64 k, hi+lo, swizzled ----
#pragma unroll
        for (int it = 0; it < NCOL / 32; ++it) {
            int id = it * 256 + tid;
            int c = id >> 3, kc = id & 7;
            const unsigned short* wp = &Wt[c * K + kt * KT + kc * 8];
            bf16x8 vh = *(const bf16x8*)wp;
            bf16x8 vl = *(const bf16x8*)(wp + NCOL * K);
            int boff = c * 128 + ((kc * 16) ^ ((c & 7) << 4));
            *(bf16x8*)((char*)Whp + boff) = vh;
            *(bf16x8*)((char*)Wlp + boff) = vl;
        }
        __syncthreads();
        // ---- compute: 2 k-steps of 32 ----
#pragma unroll
        for (int ks = 0; ks < 2; ++ks) {
            int kb = ks * 64 + lk * 16;
            bf16x8 bh[4], bl[4];
#pragma unroll
            for (int cf = 0; cf < 4; ++cf) {
                int c = wcol + cf * 16 + lr;
                int off = c * 128 + (kb ^ ((c & 7) << 4));
                bh[cf] = *(bf16x8*)((char*)Whp + off);
                bl[cf] = *(bf16x8*)((char*)Wlp + off);
            }
#pragma unroll
            for (int rf = 0; rf < WR; ++rf) {
                int r = wrow + rf * 16 + lr;
                int off = r * 128 + (kb ^ ((r & 7) << 4));
                bf16x8 ah = *(bf16x8*)((char*)Ah + off);
                bf16x8 al = *(bf16x8*)((char*)Al + off);
#pragma unroll
                for (int cf = 0; cf < 4; ++cf) {
                    acc[rf][cf] = __builtin_amdgcn_mfma_f32_16x16x32_bf16(ah, bh[cf], acc[rf][cf], 0, 0, 0);
                    acc[rf][cf] = __builtin_amdgcn_mfma_f32_16x16x32_bf16(al, bh[cf], acc[rf][cf], 0, 0, 0);
                    acc[rf][cf] = __builtin_amdgcn_mfma_f32_16x16x32_bf16(ah, bl[cf], acc[rf][cf], 0, 0, 0);
                }
            }
        }
    }
    // ---- epilogue: C frag (col=lane&15, row=(lane>>4)*4+reg), scale, bf16 ----
#pragma unroll
    for (int rf = 0; rf < WR; ++rf) {
        long rb = r0 + wrow + rf * 16 + lk * 4;
#pragma unroll
        for (int reg = 0; reg < 4; ++reg) {
            long r = rb + reg;
            if (r < N) {
                float dv = dinv[r];
#pragma unroll
                for (int cf = 0; cf < 4; ++cf) {
                    int c = wcol + cf * 16 + lr;
                    H[r * NCOL + c] = f2bf(dv * acc[rf][cf][reg]);
                }
            }
        }
    }
}

// One wave per node. F=128: lane owns 2 features (uint32 gather of bf16x2).
// F=64: lane owns 1 feature. Unweighted sum of H' rows, then *dinv[node].
template <int F, bool RELU>
__global__ __launch_bounds__(256) void k_agg(const unsigned short* __restrict__ H,
                                             const int* __restrict__ row_ptr,
                                             const int* __restrict__ col_idx,
                                             const float* __restrict__ dinv,
                                             const float* __restrict__ bias,
                                             float* __restrict__ Y, int N) {
    int lane = threadIdx.x & 63;
    int node = blockIdx.x * 4 + (threadIdx.x >> 6);
    if (node >= N) return;

    float acc0, acc1 = 0.f;
    if constexpr (F == 128) {
        uint32_t u = *(const uint32_t*)&H[(size_t)node * 128 + lane * 2];
        acc0 = bflo(u);         // self term H'[node], weight 1
        acc1 = bfhi(u);
    } else {
        acc0 = bflo((uint32_t)H[(size_t)node * F + lane]);
    }

    int start = row_ptr[node], end = row_ptr[node + 1];
    for (int base = start; base < end; base += 64) {
        int n = end - base;
        int sidx = 0;
        if (lane < n) sidx = col_idx[base + lane];
        int cnt = n < 64 ? n : 64;
        int j = 0;
        for (; j + 4 <= cnt; j += 4) {
            int s0 = __shfl(sidx, j),     s1 = __shfl(sidx, j + 1);
            int s2 = __shfl(sidx, j + 2), s3 = __shfl(sidx, j + 3);
            if constexpr (F == 128) {
                uint32_t u0 = *(const uint32_t*)&H[(size_t)s0 * 128 + lane * 2];
                uint32_t u1 = *(const uint32_t*)&H[(size_t)s1 * 128 + lane * 2];
                uint32_t u2 = *(const uint32_t*)&H[(size_t)s2 * 128 + lane * 2];
                uint32_t u3 = *(const uint32_t*)&H[(size_t)s3 * 128 + lane * 2];
                acc0 += bflo(u0); acc1 += bfhi(u0);
                acc0 += bflo(u1); acc1 += bfhi(u1);
                acc0 += bflo(u2); acc1 += bfhi(u2);
                acc0 += bflo(u3); acc1 += bfhi(u3);
            } else {
                acc0 += bflo((uint32_t)H[(size_t)s0 * F + lane]);
                acc0 += bflo((uint32_t)H[(size_t)s1 * F + lane]);
                acc0 += bflo((uint32_t)H[(size_t)s2 * F + lane]);
                acc0 += bflo((uint32_t)H[(size_t)s3 * F + lane]);
            }
        }
        for (; j < cnt; ++j) {
            int s = __shfl(sidx, j);
            if constexpr (F == 128) {
                uint32_t u = *(const uint32_t*)&H[(size_t)s * 128 + lane * 2];
                acc0 += bflo(u);
                acc1 += bfhi(u);
            } else {
                acc0 += bflo((uint32_t)H[(size_t)s * F + lane]);
            }
        }
    }

    float dv = dinv[node];
    if constexpr (F == 128) {
        float2 b = *(const float2*)&bias[lane * 2];
        float y0 = dv * acc0 + b.x, y1 = dv * acc1 + b.y;
        if (RELU) { y0 = fmaxf(y0, 0.f); y1 = fmaxf(y1, 0.f); }
        float2 o; o.x = y0; o.y = y1;
        *(float2*)&Y[(size_t)node * 128 + lane * 2] = o;
    } else {
        float y = dv * acc0 + bias[lane];
        if (RELU) y = fmaxf(y, 0.f);
        Y[(size_t)node * F + lane] = y;
    }
}

extern "C" void kernel_launch(void* const* d_in, const int* in_sizes, int n_in,
                              void* d_out, int out_size, void* d_ws, size_t ws_size,
                              hipStream_t stream) {
    const float* x  = (const float*)d_in[0];
    const int* eidx = (const int*)d_in[1];
    const float* W0 = (const float*)d_in[2];
    const float* b0 = (const float*)d_in[3];
    const float* W1 = (const float*)d_in[4];
    const float* b1 = (const float*)d_in[5];
    const float* W2 = (const float*)d_in[6];
    const float* b2 = (const float*)d_in[7];
    float* out = (float*)d_out;

    const int N = in_sizes[0] / 128;
    const int E = in_sizes[1] / 2;
    const int* srcp = eidx;
    const int* dstp = eidx + E;

    char* p = (char*)d_ws;
    auto take = [&](size_t bytes) {
        char* r = p;
        p += (bytes + 255) & ~(size_t)255;
        return r;
    };
    int*            scnt    = (int*)take((size_t)8 * N * 4);
    int*            deg     = (int*)take((size_t)N * 4);
    int*            rank    = (int*)take((size_t)E * 4);
    int*            row_ptr = (int*)take((size_t)(N + 1) * 4);
    float*          dinv    = (float*)take((size_t)N * 4);
    int*            col_idx = (int*)take((size_t)E * 4);
    unsigned short* hbuf    = (unsigned short*)take((size_t)N * 128 * 2);
    float*          ybuf    = (float*)take((size_t)N * 128 * 4);
    int*            incl    = (int*)take((size_t)N * 4);
    int*            bsum    = (int*)take((size_t)256 * 4);
    unsigned short* wt0     = (unsigned short*)take((size_t)2 * 16384 * 2);
    unsigned short* wt1     = (unsigned short*)take((size_t)2 * 16384 * 2);
    unsigned short* wt2     = (unsigned short*)take((size_t)2 * 8192 * 2);

    hipMemsetAsync(scnt, 0, (size_t)8 * N * 4, stream);

    k_deg_rank<<<(E + 255) / 256, 256, 0, stream>>>(dstp, scnt, rank, N, E);
    k_merge<<<(N + 255) / 256, 256, 0, stream>>>(scnt, deg, dinv, N);
    k_prepw<<<160, 256, 0, stream>>>(W0, W1, W2, wt0, wt1, wt2);

    int nb = (N + 1023) / 1024;  // 98 for N=100000 (must be <= 256)
    k_scan_local<<<nb, 256, 0, stream>>>(deg, incl, bsum, N);
    k_scan_tops<<<1, 256, 0, stream>>>(bsum, nb, row_ptr, N);
    k_scan_final<<<(N + 255) / 256, 256, 0, stream>>>(incl, deg, bsum, row_ptr, N);

    k_scatter<<<(E + 255) / 256, 256, 0, stream>>>(srcp, dstp, rank, row_ptr,
                                                   scnt, col_idx, N, E);

    int gemm_grid = (N + 127) / 128;
    int agg_grid  = (N + 3) / 4;

    // layer 0: h' = dinv*(x@W0) ; y = dinv*(sum h') + b0 ; relu
    k_gemm_mfma<128><<<gemm_grid, 256, 0, stream>>>(x, wt0, dinv, hbuf, N);
    k_agg<128, true><<<agg_grid, 256, 0, stream>>>(hbuf, row_ptr, col_idx,
                                                   dinv, b0, ybuf, N);
    // layer 1
    k_gemm_mfma<128><<<gemm_grid, 256, 0, stream>>>(ybuf, wt1, dinv, hbuf, N);
    k_agg<128, true><<<agg_grid, 256, 0, stream>>>(hbuf, row_ptr, col_idx,
                                                   dinv, b1, ybuf, N);
    // layer 2 (64-wide, no relu, straight to d_out)
    k_gemm_mfma<64><<<gemm_grid, 256, 0, stream>>>(ybuf, wt2, dinv, hbuf, N);
    k_agg<64, false><<<agg_grid, 256, 0, stream>>>(hbuf, row_ptr, col_idx,
                                                   dinv, b2, out, N);
}

// Round 6
// 437.429 us; speedup vs baseline: 1.0576x; 1.0576x over previous
//
#include <hip/hip_runtime.h>
#include <hip/hip_bf16.h>
#include <stdint.h>

// ---------------------------------------------------------------------------
// GCN forward: 3 layers of  out = Ahat * (X @ W) + b, relu between layers.
// Factored normalization: out[d] = dinv[d]*( sum_{s in in(d)} H'[s] + H'[d] ) + b
// where H'[i] = bf16( dinv[i] * (X@W)[i] ).
// GEMM: MFMA bf16 hi/lo split (3 mfma per product -> ~fp32 precision).
// CSR build: XCD-sharded degree+rank atomics, merge -> deg/dinv/shard-prefix,
// hierarchical scan, atomic-free scatter.
// Aggregation: wave-per-node, SPLIT-WAVE gather: lanes 0-31 = edge j,
// lanes 32-63 = edge j+1, u64 per lane (2 edges per VMEM instr), unroll x4,
// zero-row padding (no tail branches), f32 accumulate, shfl_xor combine.
// ---------------------------------------------------------------------------

typedef __attribute__((ext_vector_type(8))) short bf16x8;
typedef __attribute__((ext_vector_type(4))) float f32x4;

__device__ __forceinline__ float bflo(uint32_t u) { return __uint_as_float(u << 16); }
__device__ __forceinline__ float bfhi(uint32_t u) { return __uint_as_float(u & 0xffff0000u); }
__device__ __forceinline__ unsigned short f2bf(float f) {
    uint32_t x = __float_as_uint(f);
    return (unsigned short)((x + 0x7fffu + ((x >> 16) & 1u)) >> 16);
}

__device__ __forceinline__ int xcc_id() {
    int x;
    asm volatile("s_getreg_b32 %0, hwreg(HW_REG_XCC_ID)" : "=s"(x));
    return x & 7;
}

// degree count sharded by physical XCD + per-edge (shard,rank) pack
__global__ __launch_bounds__(256) void k_deg_rank(const int* __restrict__ dst,
                                                  int* __restrict__ scnt,
                                                  int* __restrict__ rank,
                                                  int N, int E) {
    int e = blockIdx.x * 256 + threadIdx.x;
    int xc = xcc_id();
    if (e < E) {
        int r = atomicAdd(&scnt[xc * N + dst[e]], 1);
        rank[e] = (xc << 28) | r;
    }
}

// shard counts -> exclusive shard prefix (in place); deg, dinv out.
// Also zeroes the 256-byte dummy row at hbuf[N*128 ..] (gather tail padding).
__global__ __launch_bounds__(256) void k_merge(int* __restrict__ scnt,
                                               int* __restrict__ deg,
                                               float* __restrict__ dinv,
                                               unsigned short* __restrict__ hzero,
                                               int N) {
    int i = blockIdx.x * 256 + threadIdx.x;
    if (blockIdx.x == 0 && threadIdx.x < 16) {
        uint4 z; z.x = 0; z.y = 0; z.z = 0; z.w = 0;
        ((uint4*)hzero)[threadIdx.x] = z;
    }
    if (i >= N) return;
    int sum = 0;
#pragma unroll
    for (int s = 0; s < 8; ++s) {
        int c = scnt[s * N + i];
        scnt[s * N + i] = sum;
        sum += c;
    }
    deg[i] = sum;
    dinv[i] = rsqrtf((float)(sum + 1));  // +1 self-loop
}

// ---- hierarchical scan: 1024 elements per block ---------------------------
__global__ __launch_bounds__(256) void k_scan_local(const int* __restrict__ deg,
                                                    int* __restrict__ incl,
                                                    int* __restrict__ bsum, int N) {
    __shared__ int part[256];
    int t = threadIdx.x;
    int idx0 = blockIdx.x * 1024 + t * 4;
    int4 lv = {0, 0, 0, 0};
    if (idx0 + 4 <= N) {
        lv = *(const int4*)&deg[idx0];
    } else {
        int* pv = (int*)&lv;
        for (int i = 0; i < 4; ++i) pv[i] = (idx0 + i < N) ? deg[idx0 + i] : 0;
    }
    int s = lv.x + lv.y + lv.z + lv.w;
    part[t] = s;
    __syncthreads();
    for (int off = 1; off < 256; off <<= 1) {
        int x = (t >= off) ? part[t - off] : 0;
        __syncthreads();
        part[t] += x;
        __syncthreads();
    }
    int run = (t == 0) ? 0 : part[t - 1];
    if (t == 255) bsum[blockIdx.x] = part[255];
    int4 ov;
    ov.x = run + lv.x;
    ov.y = ov.x + lv.y;
    ov.z = ov.y + lv.z;
    ov.w = ov.z + lv.w;
    if (idx0 + 4 <= N) {
        *(int4*)&incl[idx0] = ov;
    } else {
        int* po = (int*)&ov;
        for (int i = 0; i < 4; ++i)
            if (idx0 + i < N) incl[idx0 + i] = po[i];
    }
}

// exclusive scan of up to 256 block sums; also writes row_ptr[N] = total
__global__ __launch_bounds__(256) void k_scan_tops(int* __restrict__ bsum, int nb,
                                                   int* __restrict__ row_ptr, int N) {
    __shared__ int part[256];
    int t = threadIdx.x;
    int v = (t < nb) ? bsum[t] : 0;
    part[t] = v;
    __syncthreads();
    for (int off = 1; off < 256; off <<= 1) {
        int x = (t >= off) ? part[t - off] : 0;
        __syncthreads();
        part[t] += x;
        __syncthreads();
    }
    if (t < nb) bsum[t] = part[t] - v;   // exclusive
    if (t == 255) row_ptr[N] = part[255];
}

__global__ __launch_bounds__(256) void k_scan_final(const int* __restrict__ incl,
                                                    const int* __restrict__ deg,
                                                    const int* __restrict__ bsum,
                                                    int* __restrict__ row_ptr, int N) {
    int i = blockIdx.x * 256 + threadIdx.x;
    if (i < N) row_ptr[i] = incl[i] - deg[i] + bsum[i >> 10];
}

// atomic-free scatter: pos = row_ptr[dst] + shard_prefix + local rank
__global__ __launch_bounds__(256) void k_scatter(const int* __restrict__ src,
                                                 const int* __restrict__ dst,
                                                 const int* __restrict__ rank,
                                                 const int* __restrict__ row_ptr,
                                                 const int* __restrict__ scnt,
                                                 int* __restrict__ col_idx,
                                                 int N, int E) {
    int e = blockIdx.x * 256 + threadIdx.x;
    if (e < E) {
        int d = dst[e];
        int pr = rank[e];
        int s = pr >> 28, lr = pr & 0x0fffffff;
        col_idx[row_ptr[d] + scnt[s * N + d] + lr] = src[e];
    }
}

// W [K][M] f32 -> Wt_hi[c][k], Wt_lo[c][k] bf16 (transposed, hi plane then lo)
__global__ __launch_bounds__(256) void k_prepw(const float* __restrict__ W0,
                                               const float* __restrict__ W1,
                                               const float* __restrict__ W2,
                                               unsigned short* __restrict__ wt0,
                                               unsigned short* __restrict__ wt1,
                                               unsigned short* __restrict__ wt2) {
    int id = blockIdx.x * 256 + threadIdx.x;
    const float* Wsrc;
    unsigned short* dst;
    int t, M, plane;
    if (id < 16384)      { t = id;         Wsrc = W0; dst = wt0; M = 128; plane = 16384; }
    else if (id < 32768) { t = id - 16384; Wsrc = W1; dst = wt1; M = 128; plane = 16384; }
    else if (id < 40960) { t = id - 32768; Wsrc = W2; dst = wt2; M = 64;  plane = 8192;  }
    else return;
    int k = (M == 128) ? (t >> 7) : (t >> 6);
    int c = (M == 128) ? (t & 127) : (t & 63);
    float v = Wsrc[k * M + c];
    unsigned short hi = f2bf(v);
    float lov = v - bflo((uint32_t)hi);
    dst[c * 128 + k]         = hi;
    dst[plane + c * 128 + k] = f2bf(lov);
}

// H[r,:] = bf16( dinv[r] * (A[r,:] @ W) ) via split-bf16 MFMA.
// A f32 [N,128]; Wt = transposed hi/lo bf16 [NCOL][128] x2; H bf16 [N,NCOL].
// Block: 256 thr / 4 waves, tile 128 rows x NCOL cols, K-tiled by 64.
template <int NCOL>
__global__ __launch_bounds__(256) void k_gemm_mfma(
    const float* __restrict__ A, const unsigned short* __restrict__ Wt,
    const float* __restrict__ dinv, unsigned short* __restrict__ H, int N) {
    constexpr int K = 128, KT = 64;
    constexpr int A_PLANE = 128 * KT;     // shorts
    constexpr int W_PLANE = NCOL * KT;
    __shared__ __align__(16) unsigned short sm[2 * A_PLANE + 2 * W_PLANE];  // 64/48 KB
    unsigned short* Ah  = sm;
    unsigned short* Al  = sm + A_PLANE;
    unsigned short* Whp = sm + 2 * A_PLANE;
    unsigned short* Wlp = sm + 2 * A_PLANE + W_PLANE;

    const int tid = threadIdx.x;
    const long r0 = (long)blockIdx.x * 128;
    const int w = tid >> 6, l = tid & 63;
    const int lr = l & 15, lk = l >> 4;
    constexpr int WR = (NCOL == 128) ? 4 : 2;          // 16-row frags per wave
    const int wrow = (NCOL == 128) ? (w >> 1) * 64 : w * 32;
    const int wcol = (NCOL == 128) ? (w & 1) * 64 : 0;

    f32x4 acc[WR][4];
#pragma unroll
    for (int i = 0; i < WR; ++i)
#pragma unroll
        for (int j = 0; j < 4; ++j) acc[i][j] = (f32x4){0.f, 0.f, 0.f, 0.f};

    for (int kt = 0; kt < 2; ++kt) {
        if (kt) __syncthreads();           // previous compute done
        // ---- stage A tile: 128 rows x 64 k, f32 -> hi/lo bf16, swizzled ----
#pragma unroll
        for (int it = 0; it < 4; ++it) {
            int id = it * 256 + tid;
            int r = id >> 3, kc = id & 7;   // 8 chunks of 8 f32 per row
            long gr = r0 + r;
            if (gr >= N) gr = N - 1;
            const float* ap = &A[gr * K + kt * KT + kc * 8];
            float4 v0 = *(const float4*)ap;
            float4 v1 = *(const float4*)(ap + 4);
            float vv[8] = {v0.x, v0.y, v0.z, v0.w, v1.x, v1.y, v1.z, v1.w};
            union { unsigned short u[8]; bf16x8 v; } ph, pl;
#pragma unroll
            for (int j = 0; j < 8; ++j) {
                unsigned short h = f2bf(vv[j]);
                ph.u[j] = h;
                pl.u[j] = f2bf(vv[j] - bflo((uint32_t)h));
            }
            int boff = r * 128 + ((kc * 16) ^ ((r & 7) << 4));
            *(bf16x8*)((char*)Ah + boff) = ph.v;
            *(bf16x8*)((char*)Al + boff) = pl.v;
        }
        // ---- stage W tile: NCOL rows x 64 k, hi+lo, swizzled ----
#pragma unroll
        for (int it = 0; it < NCOL / 32; ++it) {
            int id = it * 256 + tid;
            int c = id >> 3, kc = id & 7;
            const unsigned short* wp = &Wt[c * K + kt * KT + kc * 8];
            bf16x8 vh = *(const bf16x8*)wp;
            bf16x8 vl = *(const bf16x8*)(wp + NCOL * K);
            int boff = c * 128 + ((kc * 16) ^ ((c & 7) << 4));
            *(bf16x8*)((char*)Whp + boff) = vh;
            *(bf16x8*)((char*)Wlp + boff) = vl;
        }
        __syncthreads();
        // ---- compute: 2 k-steps of 32 ----
#pragma unroll
        for (int ks = 0; ks < 2; ++ks) {
            int kb = ks * 64 + lk * 16;
            bf16x8 bh[4], bl[4];
#pragma unroll
            for (int cf = 0; cf < 4; ++cf) {
                int c = wcol + cf * 16 + lr;
                int off = c * 128 + (kb ^ ((c & 7) << 4));
                bh[cf] = *(bf16x8*)((char*)Whp + off);
                bl[cf] = *(bf16x8*)((char*)Wlp + off);
            }
#pragma unroll
            for (int rf = 0; rf < WR; ++rf) {
                int r = wrow + rf * 16 + lr;
                int off = r * 128 + (kb ^ ((r & 7) << 4));
                bf16x8 ah = *(bf16x8*)((char*)Ah + off);
                bf16x8 al = *(bf16x8*)((char*)Al + off);
#pragma unroll
                for (int cf = 0; cf < 4; ++cf) {
                    acc[rf][cf] = __builtin_amdgcn_mfma_f32_16x16x32_bf16(ah, bh[cf], acc[rf][cf], 0, 0, 0);
                    acc[rf][cf] = __builtin_amdgcn_mfma_f32_16x16x32_bf16(al, bh[cf], acc[rf][cf], 0, 0, 0);
                    acc[rf][cf] = __builtin_amdgcn_mfma_f32_16x16x32_bf16(ah, bl[cf], acc[rf][cf], 0, 0, 0);
                }
            }
        }
    }
    // ---- epilogue: C frag (col=lane&15, row=(lane>>4)*4+reg), scale, bf16 ----
#pragma unroll
    for (int rf = 0; rf < WR; ++rf) {
        long rb = r0 + wrow + rf * 16 + lk * 4;
#pragma unroll
        for (int reg = 0; reg < 4; ++reg) {
            long r = rb + reg;
            if (r < N) {
                float dv = dinv[r];
#pragma unroll
                for (int cf = 0; cf < 4; ++cf) {
                    int c = wcol + cf * 16 + lr;
                    H[r * NCOL + c] = f2bf(dv * acc[rf][cf][reg]);
                }
            }
        }
    }
}

// One wave per node, split halves: lanes 0-31 = even edge, 32-63 = odd edge.
// F=128: lane owns 4 features (u64 gather); F=64: 2 features (u32 gather).
// Tail edges padded with DUMMY index -> zero row (no branches in inner loop).
template <int F, bool RELU>
__global__ __launch_bounds__(256) void k_agg(const unsigned short* __restrict__ H,
                                             const int* __restrict__ row_ptr,
                                             const int* __restrict__ col_idx,
                                             const float* __restrict__ dinv,
                                             const float* __restrict__ bias,
                                             float* __restrict__ Y, int N) {
    constexpr int FL = F / 32;          // floats per lane: 4 (F=128) / 2 (F=64)
    int lane = threadIdx.x & 63;
    int node = blockIdx.x * 4 + (threadIdx.x >> 6);
    if (node >= N) return;
    const int half = lane >> 5, hl = lane & 31;
    const int DUMMY = (F == 128) ? N : 2 * N;   // both map to the zero row

    float acc[FL];
    if constexpr (F == 128) {
        if (half == 0) {
            uint64_t u = *(const uint64_t*)&H[(size_t)node * 128 + hl * 4];
            acc[0] = bflo((uint32_t)u);         acc[1] = bfhi((uint32_t)u);
            acc[2] = bflo((uint32_t)(u >> 32)); acc[3] = bfhi((uint32_t)(u >> 32));
        } else { acc[0] = acc[1] = acc[2] = acc[3] = 0.f; }
    } else {
        if (half == 0) {
            uint32_t u = *(const uint32_t*)&H[(size_t)node * 64 + hl * 2];
            acc[0] = bflo(u); acc[1] = bfhi(u);
        } else { acc[0] = acc[1] = 0.f; }
    }

    int start = row_ptr[node], end = row_ptr[node + 1];
    for (int base = start; base < end; base += 64) {
        int idx = DUMMY;
        if (base + lane < end) idx = col_idx[base + lane];
        int cnt = min(64, end - base);
        for (int j = 0; j < cnt; j += 8) {      // 8 edges per iter (2 per pass)
            int s0 = __shfl(idx, j + half);
            int s1 = __shfl(idx, j + 2 + half);
            int s2 = __shfl(idx, j + 4 + half);
            int s3 = __shfl(idx, j + 6 + half);
            if constexpr (F == 128) {
                uint64_t u0 = *(const uint64_t*)&H[(size_t)s0 * 128 + hl * 4];
                uint64_t u1 = *(const uint64_t*)&H[(size_t)s1 * 128 + hl * 4];
                uint64_t u2 = *(const uint64_t*)&H[(size_t)s2 * 128 + hl * 4];
                uint64_t u3 = *(const uint64_t*)&H[(size_t)s3 * 128 + hl * 4];
                acc[0] += bflo((uint32_t)u0);         acc[1] += bfhi((uint32_t)u0);
                acc[2] += bflo((uint32_t)(u0 >> 32)); acc[3] += bfhi((uint32_t)(u0 >> 32));
                acc[0] += bflo((uint32_t)u1);         acc[1] += bfhi((uint32_t)u1);
                acc[2] += bflo((uint32_t)(u1 >> 32)); acc[3] += bfhi((uint32_t)(u1 >> 32));
                acc[0] += bflo((uint32_t)u2);         acc[1] += bfhi((uint32_t)u2);
                acc[2] += bflo((uint32_t)(u2 >> 32)); acc[3] += bfhi((uint32_t)(u2 >> 32));
                acc[0] += bflo((uint32_t)u3);         acc[1] += bfhi((uint32_t)u3);
                acc[2] += bflo((uint32_t)(u3 >> 32)); acc[3] += bfhi((uint32_t)(u3 >> 32));
            } else {
                uint32_t u0 = *(const uint32_t*)&H[(size_t)s0 * 64 + hl * 2];
                uint32_t u1 = *(const uint32_t*)&H[(size_t)s1 * 64 + hl * 2];
                uint32_t u2 = *(const uint32_t*)&H[(size_t)s2 * 64 + hl * 2];
                uint32_t u3 = *(const uint32_t*)&H[(size_t)s3 * 64 + hl * 2];
                acc[0] += bflo(u0); acc[1] += bfhi(u0);
                acc[0] += bflo(u1); acc[1] += bfhi(u1);
                acc[0] += bflo(u2); acc[1] += bfhi(u2);
                acc[0] += bflo(u3); acc[1] += bfhi(u3);
            }
        }
    }

    // combine halves: lane<32 gets lane+32's partial, writes result
    float part[FL];
#pragma unroll
    for (int f = 0; f < FL; ++f) part[f] = __shfl_xor(acc[f], 32);
    if (half == 0) {
        float dv = dinv[node];
        if constexpr (F == 128) {
            float4 b = *(const float4*)&bias[hl * 4];
            float4 o;
            o.x = dv * (acc[0] + part[0]) + b.x;
            o.y = dv * (acc[1] + part[1]) + b.y;
            o.z = dv * (acc[2] + part[2]) + b.z;
            o.w = dv * (acc[3] + part[3]) + b.w;
            if (RELU) {
                o.x = fmaxf(o.x, 0.f); o.y = fmaxf(o.y, 0.f);
                o.z = fmaxf(o.z, 0.f); o.w = fmaxf(o.w, 0.f);
            }
            *(float4*)&Y[(size_t)node * 128 + hl * 4] = o;
        } else {
            float2 b = *(const float2*)&bias[hl * 2];
            float2 o;
            o.x = dv * (acc[0] + part[0]) + b.x;
            o.y = dv * (acc[1] + part[1]) + b.y;
            if (RELU) { o.x = fmaxf(o.x, 0.f); o.y = fmaxf(o.y, 0.f); }
            *(float2*)&Y[(size_t)node * 64 + hl * 2] = o;
        }
    }
}

extern "C" void kernel_launch(void* const* d_in, const int* in_sizes, int n_in,
                              void* d_out, int out_size, void* d_ws, size_t ws_size,
                              hipStream_t stream) {
    const float* x  = (const float*)d_in[0];
    const int* eidx = (const int*)d_in[1];
    const float* W0 = (const float*)d_in[2];
    const float* b0 = (const float*)d_in[3];
    const float* W1 = (const float*)d_in[4];
    const float* b1 = (const float*)d_in[5];
    const float* W2 = (const float*)d_in[6];
    const float* b2 = (const float*)d_in[7];
    float* out = (float*)d_out;

    const int N = in_sizes[0] / 128;
    const int E = in_sizes[1] / 2;
    const int* srcp = eidx;
    const int* dstp = eidx + E;

    char* p = (char*)d_ws;
    auto take = [&](size_t bytes) {
        char* r = p;
        p += (bytes + 255) & ~(size_t)255;
        return r;
    };
    int*            scnt    = (int*)take((size_t)8 * N * 4);
    int*            deg     = (int*)take((size_t)N * 4);
    int*            rank    = (int*)take((size_t)E * 4);
    int*            row_ptr = (int*)take((size_t)(N + 1) * 4);
    float*          dinv    = (float*)take((size_t)N * 4);
    int*            col_idx = (int*)take((size_t)E * 4);
    unsigned short* hbuf    = (unsigned short*)take((size_t)(N + 1) * 128 * 2);
    float*          ybuf    = (float*)take((size_t)N * 128 * 4);
    int*            incl    = (int*)take((size_t)N * 4);
    int*            bsum    = (int*)take((size_t)256 * 4);
    unsigned short* wt0     = (unsigned short*)take((size_t)2 * 16384 * 2);
    unsigned short* wt1     = (unsigned short*)take((size_t)2 * 16384 * 2);
    unsigned short* wt2     = (unsigned short*)take((size_t)2 * 8192 * 2);

    hipMemsetAsync(scnt, 0, (size_t)8 * N * 4, stream);

    k_deg_rank<<<(E + 255) / 256, 256, 0, stream>>>(dstp, scnt, rank, N, E);
    k_merge<<<(N + 255) / 256, 256, 0, stream>>>(scnt, deg, dinv,
                                                 hbuf + (size_t)N * 128, N);
    k_prepw<<<160, 256, 0, stream>>>(W0, W1, W2, wt0, wt1, wt2);

    int nb = (N + 1023) / 1024;  // 98 for N=100000 (must be <= 256)
    k_scan_local<<<nb, 256, 0, stream>>>(deg, incl, bsum, N);
    k_scan_tops<<<1, 256, 0, stream>>>(bsum, nb, row_ptr, N);
    k_scan_final<<<(N + 255) / 256, 256, 0, stream>>>(incl, deg, bsum, row_ptr, N);

    k_scatter<<<(E + 255) / 256, 256, 0, stream>>>(srcp, dstp, rank, row_ptr,
                                                   scnt, col_idx, N, E);

    int gemm_grid = (N + 127) / 128;
    int agg_grid  = (N + 3) / 4;

    // layer 0: h' = dinv*(x@W0) ; y = dinv*(sum h') + b0 ; relu
    k_gemm_mfma<128><<<gemm_grid, 256, 0, stream>>>(x, wt0, dinv, hbuf, N);
    k_agg<128, true><<<agg_grid, 256, 0, stream>>>(hbuf, row_ptr, col_idx,
                                                   dinv, b0, ybuf, N);
    // layer 1
    k_gemm_mfma<128><<<gemm_grid, 256, 0, stream>>>(ybuf, wt1, dinv, hbuf, N);
    k_agg<128, true><<<agg_grid, 256, 0, stream>>>(hbuf, row_ptr, col_idx,
                                                   dinv, b1, ybuf, N);
    // layer 2 (64-wide, no relu, straight to d_out)
    k_gemm_mfma<64><<<gemm_grid, 256, 0, stream>>>(ybuf, wt2, dinv, hbuf, N);
    k_agg<64, false><<<agg_grid, 256, 0, stream>>>(hbuf, row_ptr, col_idx,
                                                   dinv, b2, out, N);
}